// Round 1
// baseline (326.787 us; speedup 1.0000x reference)
//
#include <hip/hip_runtime.h>
#include <hip/hip_bf16.h>
#include <math.h>

#define BN 32
#define L 128
#define D 128
#define TT 127
#define NH 8
#define HD 16

__device__ __forceinline__ float gelu_f(float x) {
    return 0.5f * x * (1.0f + erff(x * 0.70710678118654752f));
}

// Kernel 1: QKV projection. grid (BN, 3, 4), block 256.
__global__ __launch_bounds__(256)
void qkv_kernel(const float* __restrict__ padded, const float* __restrict__ tok,
                const float* __restrict__ Wq, const float* __restrict__ bq,
                const float* __restrict__ Wk, const float* __restrict__ bk,
                const float* __restrict__ Wv, const float* __restrict__ bv,
                float* __restrict__ Qo, float* __restrict__ KTo, float* __restrict__ Vo) {
    const int s = blockIdx.x;
    const int mat = blockIdx.y;
    const int chunk = blockIdx.z;
    const float* W = (mat == 0) ? Wq : (mat == 1) ? Wk : Wv;
    const float* bias = (mat == 0) ? bq : (mat == 1) ? bk : bv;

    __shared__ float x_tile[32][D];
    const int tid = threadIdx.x;
    for (int idx = tid; idx < 32 * D; idx += 256) {
        int r = idx >> 7, c = idx & 127;
        int i = chunk * 32 + r;
        x_tile[r][c] = (i == 0) ? tok[c] : padded[(size_t)s * TT * D + (size_t)(i - 1) * D + c];
    }
    __syncthreads();

    const int c = tid & 127;
    const int rg = tid >> 7;   // 0 or 1
    const int r0 = rg * 16;
    float acc[16];
    const float bc = bias[c];
#pragma unroll
    for (int r = 0; r < 16; ++r) acc[r] = bc;
    for (int d = 0; d < D; ++d) {
        float wv = W[d * D + c];
#pragma unroll
        for (int r = 0; r < 16; ++r) acc[r] = fmaf(x_tile[r0 + r][d], wv, acc[r]);
    }
    size_t base = (size_t)s * L * D;
    if (mat == 1) {
        for (int r = 0; r < 16; ++r)
            KTo[base + (size_t)c * L + (size_t)(chunk * 32 + r0 + r)] = acc[r];
    } else {
        float* outp = (mat == 0) ? Qo : Vo;
        for (int r = 0; r < 16; ++r)
            outp[base + (size_t)(chunk * 32 + r0 + r) * D + c] = acc[r];
    }
}

// Kernel 2: one block per (i, s); 128 threads, thread j = key index.
__global__ __launch_bounds__(128)
void attn_kernel(const float* __restrict__ padded, const int* __restrict__ masks,
                 const float* __restrict__ pos3d,
                 const float* __restrict__ gamma, const float* __restrict__ beta,
                 const float* __restrict__ tok,
                 const float* __restrict__ Wb1, const float* __restrict__ bb1,
                 const float* __restrict__ Wb2, const float* __restrict__ bb2,
                 const float* __restrict__ Wv1, const float* __restrict__ bv1,
                 const float* __restrict__ Wv2, const float* __restrict__ bv2,
                 const float* __restrict__ Q, const float* __restrict__ KT,
                 const float* __restrict__ V,
                 float* __restrict__ out) {
    const int i = blockIdx.x;
    const int s = blockIdx.y;
    const int j = threadIdx.x;
    const int wave = j >> 6;

    __shared__ float q_lds[D];
    __shared__ float wb1s[5][64];
    __shared__ float bb1s[64];
    __shared__ float wb2s[64][NH];
    __shared__ float bb2s[NH];
    __shared__ float wv1s[5][128];
    __shared__ float bv1s[128];
    __shared__ __hip_bfloat16 g_lds[L][D];
    __shared__ float w_lds[NH][L];
    __shared__ float gs_lds[NH][D];
    __shared__ float redm[2][NH];
    __shared__ float reds[2][NH];
    __shared__ float red2[2][2];

    // ---- stage small weights into LDS ----
    if (j < 64) {
        wb1s[0][j] = Wb1[0 * 64 + j];
        wb1s[1][j] = Wb1[1 * 64 + j];
        wb1s[2][j] = Wb1[2 * 64 + j];
        wb1s[3][j] = Wb1[3 * 64 + j] + Wb1[4 * 64 + j];
        wb1s[4][j] = Wb1[5 * 64 + j];
        bb1s[j] = bb1[j];
    }
    for (int idx = j; idx < 64 * NH; idx += 128) ((float*)wb2s)[idx] = Wb2[idx];
    if (j < NH) bb2s[j] = bb2[j];
    wv1s[0][j] = Wv1[0 * 128 + j];
    wv1s[1][j] = Wv1[1 * 128 + j];
    wv1s[2][j] = Wv1[2 * 128 + j];
    wv1s[3][j] = Wv1[3 * 128 + j] + Wv1[4 * 128 + j];
    wv1s[4][j] = Wv1[5 * 128 + j];
    bv1s[j] = bv1[j];
    q_lds[j] = Q[((size_t)s * L + (size_t)i) * D + j];
    __syncthreads();

    // ---- relative features ----
    float pix, piy, piz;
    if (i == 0) { pix = piy = piz = 0.f; }
    else {
        const float* p = pos3d + ((size_t)s * TT + (size_t)(i - 1)) * 3;
        pix = p[0]; piy = p[1]; piz = p[2];
    }
    float pjx, pjy, pjz;
    if (j == 0) { pjx = pjy = pjz = 0.f; }
    else {
        const float* p = pos3d + ((size_t)s * TT + (size_t)(j - 1)) * 3;
        pjx = p[0]; pjy = p[1]; pjz = p[2];
    }
    const float dx = pix - pjx, dy = piy - pjy, dz = piz - pjz;
    const float dist2 = dx * dx + dy * dy + dz * dz;
    const float dist = sqrtf(dist2);

    // ---- rel bias MLP (zeroed when i==0 or j==0) ----
    float bias[NH];
#pragma unroll
    for (int h = 0; h < NH; ++h) bias[h] = 0.f;
    if (i > 0 && j > 0) {
        for (int u = 0; u < 64; ++u) {
            float hv = bb1s[u];
            hv = fmaf(dx, wb1s[0][u], hv);
            hv = fmaf(dy, wb1s[1][u], hv);
            hv = fmaf(dz, wb1s[2][u], hv);
            hv = fmaf(dist, wb1s[3][u], hv);
            hv = fmaf(dist2, wb1s[4][u], hv);
            hv = gelu_f(hv);
#pragma unroll
            for (int h = 0; h < NH; ++h) bias[h] = fmaf(hv, wb2s[u][h], bias[h]);
        }
#pragma unroll
        for (int h = 0; h < NH; ++h) bias[h] += bb2s[h];
    }

    // ---- rel-val hidden g -> LDS (bf16); only needed when i>0 ----
    if (i > 0) {
        for (int c = 0; c < D; ++c) {
            float hv = bv1s[c];
            hv = fmaf(dx, wv1s[0][c], hv);
            hv = fmaf(dy, wv1s[1][c], hv);
            hv = fmaf(dz, wv1s[2][c], hv);
            hv = fmaf(dist, wv1s[3][c], hv);
            hv = fmaf(dist2, wv1s[4][c], hv);
            g_lds[j][c] = __float2bfloat16(gelu_f(hv));
        }
    }

    // ---- logits: q . k per head, via K^T (coalesced in j) ----
    float l[NH];
    const float* KTs = KT + (size_t)s * L * D;
#pragma unroll
    for (int h = 0; h < NH; ++h) {
        float acc = 0.f;
#pragma unroll
        for (int d = 0; d < HD; ++d) {
            int c = h * HD + d;
            acc = fmaf(q_lds[c], KTs[(size_t)c * L + j], acc);
        }
        l[h] = acc;
    }
    const int keep = (j == 0) ? 1 : masks[(size_t)s * TT + (j - 1)];
#pragma unroll
    for (int h = 0; h < NH; ++h) {
        l[h] = l[h] * 0.25f + bias[h];
        if (!keep) l[h] = -3.0e38f;
    }

    // ---- softmax across the 128 threads (2 waves) ----
    float m[NH];
#pragma unroll
    for (int h = 0; h < NH; ++h) {
        float v = l[h];
        for (int off = 32; off >= 1; off >>= 1) v = fmaxf(v, __shfl_xor(v, off, 64));
        m[h] = v;
    }
    if ((j & 63) == 0) {
#pragma unroll
        for (int h = 0; h < NH; ++h) redm[wave][h] = m[h];
    }
    __syncthreads();
#pragma unroll
    for (int h = 0; h < NH; ++h) m[h] = fmaxf(redm[0][h], redm[1][h]);

    float p[NH];
#pragma unroll
    for (int h = 0; h < NH; ++h) {
        p[h] = __expf(l[h] - m[h]);
        float v = p[h];
        for (int off = 32; off >= 1; off >>= 1) v += __shfl_xor(v, off, 64);
        if ((j & 63) == 0) reds[wave][h] = v;
    }
    __syncthreads();
#pragma unroll
    for (int h = 0; h < NH; ++h) {
        float inv = 1.0f / (reds[0][h] + reds[1][h]);
        w_lds[h][j] = p[h] * inv;
    }
    __syncthreads();   // w_lds + g_lds ready

    // ---- reduction phase: thread j owns output channel j (h = j/16) ----
    const int h = j >> 4;
    const int c0 = j & 15;
    const float* Vs = V + (size_t)s * L * D;
    float a1 = 0.f;
    for (int jj = 0; jj < L; ++jj)
        a1 = fmaf(w_lds[h][jj], Vs[(size_t)jj * D + j], a1);

    if (i > 0) {
        float gs[8];
#pragma unroll
        for (int cc = 0; cc < 8; ++cc) gs[cc] = 0.f;
        for (int jj = 1; jj < L; ++jj) {
            float wj = w_lds[h][jj];
#pragma unroll
            for (int cc = 0; cc < 8; ++cc)
                gs[cc] = fmaf(wj, __bfloat162float(g_lds[jj][c0 + cc * 16]), gs[cc]);
        }
#pragma unroll
        for (int cc = 0; cc < 8; ++cc) gs_lds[h][c0 + cc * 16] = gs[cc];
    }
    __syncthreads();

    float a2 = 0.f;
    if (i > 0) {
        const float S1 = 1.0f - w_lds[h][0];
        for (int c = 0; c < D; ++c)
            a2 = fmaf(gs_lds[h][c], Wv2[(size_t)c * D + j], a2);
        a2 = fmaf(S1, bv2[j], a2);
    }
    const float attn = a1 + a2;

    // ---- outputs ----
    if (i == 0) {
        float st = attn + tok[j];
        float sum = st, sum2 = st * st;
        for (int off = 32; off >= 1; off >>= 1) {
            sum += __shfl_xor(sum, off, 64);
            sum2 += __shfl_xor(sum2, off, 64);
        }
        if ((j & 63) == 0) { red2[wave][0] = sum; red2[wave][1] = sum2; }
        __syncthreads();
        sum = red2[0][0] + red2[1][0];
        sum2 = red2[0][1] + red2[1][1];
        const float mu = sum * (1.0f / 128.0f);
        const float var = sum2 * (1.0f / 128.0f) - mu * mu;
        const float y = (st - mu) * rsqrtf(var + 1e-5f) * gamma[j] + beta[j];
        out[(size_t)BN * TT * D + (size_t)s * D + j] = y;
    } else {
        const size_t o = (size_t)s * TT * D + (size_t)(i - 1) * D + j;
        out[o] = attn + padded[o];
    }
}

extern "C" void kernel_launch(void* const* d_in, const int* in_sizes, int n_in,
                              void* d_out, int out_size, void* d_ws, size_t ws_size,
                              hipStream_t stream) {
    const float* padded = (const float*)d_in[0];
    const int*   masks  = (const int*)d_in[1];
    const float* pos3d  = (const float*)d_in[2];
    const float* Wq = (const float*)d_in[3];
    const float* bq = (const float*)d_in[4];
    const float* Wk = (const float*)d_in[5];
    const float* bk = (const float*)d_in[6];
    const float* Wv = (const float*)d_in[7];
    const float* bv = (const float*)d_in[8];
    const float* gamma = (const float*)d_in[9];
    const float* beta  = (const float*)d_in[10];
    const float* tok   = (const float*)d_in[11];
    const float* Wb1 = (const float*)d_in[12];
    const float* bb1 = (const float*)d_in[13];
    const float* Wb2 = (const float*)d_in[14];
    const float* bb2 = (const float*)d_in[15];
    const float* Wv1 = (const float*)d_in[16];
    const float* bv1 = (const float*)d_in[17];
    const float* Wv2 = (const float*)d_in[18];
    const float* bv2 = (const float*)d_in[19];
    float* out = (float*)d_out;

    float* Q  = (float*)d_ws;
    float* KT = Q + (size_t)BN * L * D;
    float* Vw = KT + (size_t)BN * L * D;

    qkv_kernel<<<dim3(BN, 3, 4), 256, 0, stream>>>(padded, tok, Wq, bq, Wk, bk, Wv, bv, Q, KT, Vw);
    attn_kernel<<<dim3(L, BN), 128, 0, stream>>>(padded, masks, pos3d, gamma, beta, tok,
                                                 Wb1, bb1, Wb2, bb2, Wv1, bv1, Wv2, bv2,
                                                 Q, KT, Vw, out);
}